// Round 4
// baseline (348.664 us; speedup 1.0000x reference)
//
#include <hip/hip_runtime.h>

// Head: fused QKV projection + causal attention, MI355X (gfx950)
// B=512, T=256, C=384, D=64. fp32 in/out, bf16 MFMA compute.

typedef short s16x8 __attribute__((ext_vector_type(8)));
typedef float f32x4 __attribute__((ext_vector_type(4)));
typedef unsigned short u16;
typedef unsigned short u16x4 __attribute__((ext_vector_type(4)));

__device__ __forceinline__ u16 f2bf(float f) {
  unsigned u = __builtin_bit_cast(unsigned, f);
  u = (u + 0x7fffu + ((u >> 16) & 1u)) >> 16;   // RNE
  return (u16)u;
}

__device__ __forceinline__ s16x8 pack8(float4 a, float4 b) {
  s16x8 h;
  h[0] = (short)f2bf(a.x); h[1] = (short)f2bf(a.y);
  h[2] = (short)f2bf(a.z); h[3] = (short)f2bf(a.w);
  h[4] = (short)f2bf(b.x); h[5] = (short)f2bf(b.y);
  h[6] = (short)f2bf(b.z); h[7] = (short)f2bf(b.w);
  return h;
}

#define MFMA16 __builtin_amdgcn_mfma_f32_16x16x32_bf16

// ---------------------------------------------------------------------------
// Kernel 1: QKV projection. x[131072][384] f32 -> Q,K,V bf16 [131072][64].
// Full W (192x384 bf16 = 144 KiB) staged to LDS ONCE (swizzled), one barrier,
// then a barrier-free streaming loop. Persistent reg state is only acc[12]
// (48 VGPR) + depth-2 x prefetch (16) -> no spill at 128 VGPR (the round-2/3
// failure mode). Per kc: one 32B/lane x load (f32->bf16 in flight),
// 12 ds_read_b128 W-frags, 12 MFMA (A=W-frag, B=x-frag).
// C/D layout: col=lane&15 <-> x-row (the row this lane loaded), row <-> n.
// 512 thr (8 waves), grid 256 = 1 block/CU (LDS-capped); wave does 4 strips
// of 16 rows; strips interleaved so the block sweeps 128-row panels.
// ---------------------------------------------------------------------------
__global__ __launch_bounds__(512, 2) void qkv_kernel(
    const float* __restrict__ x,
    const float* __restrict__ WQ, const float* __restrict__ WK,
    const float* __restrict__ WV,
    u16* __restrict__ Qo, u16* __restrict__ Ko, u16* __restrict__ Vo)
{
  __shared__ char wlds[192 * 768];   // 144 KiB: row n (0..191), 384 bf16/row
  const int tid = threadIdx.x;
  const int l  = tid & 63;
  const int w  = tid >> 6;
  const int g  = l >> 4, li = l & 15;

  // ---- stage W once: 192 rows x 48 slots of 8 f32 -> bf16, swizzled ----
#pragma unroll
  for (int i = 0; i < 18; ++i) {
    int id = tid + 512 * i;             // 0..9215
    int row = id / 48, slot = id - row * 48;
    const float* wsrc = (row < 64) ? (WQ + row * 384)
                       : (row < 128) ? (WK + (row - 64) * 384)
                                     : (WV + (row - 128) * 384);
    const float4* src = reinterpret_cast<const float4*>(wsrc + slot * 8);
    float4 a = src[0], b = src[1];
    *reinterpret_cast<s16x8*>(wlds + row * 768 + ((slot ^ (row & 7)) << 4)) =
        pack8(a, b);
  }
  __syncthreads();

  const long rowbase = (long)blockIdx.x * 512;

#pragma unroll 1
  for (int sp = 0; sp < 4; ++sp) {
    const long mrow = rowbase + (sp * 8 + w) * 16 + li;   // this lane's row
    const float* px = x + mrow * 384 + g * 8;

    f32x4 acc[12];
#pragma unroll
    for (int nt = 0; nt < 12; ++nt) acc[nt] = (f32x4){0.f, 0.f, 0.f, 0.f};

    // depth-2 pipeline on the x stream
    float4 a0 = *reinterpret_cast<const float4*>(px);
    float4 a1 = *reinterpret_cast<const float4*>(px + 4);
    float4 b0 = *reinterpret_cast<const float4*>(px + 32);
    float4 b1 = *reinterpret_cast<const float4*>(px + 36);

#pragma unroll
    for (int kc = 0; kc < 12; ++kc) {
      s16x8 xf = pack8(a0, a1);
      a0 = b0; a1 = b1;
      if (kc < 10) {
        b0 = *reinterpret_cast<const float4*>(px + (kc + 2) * 32);
        b1 = *reinterpret_cast<const float4*>(px + (kc + 2) * 32 + 4);
      }
#pragma unroll
      for (int nt = 0; nt < 12; ++nt) {
        int rw = nt * 16 + li;
        s16x8 bf = *reinterpret_cast<const s16x8*>(
            wlds + rw * 768 + (((kc * 4 + g) ^ (li & 7)) << 4));
        acc[nt] = MFMA16(bf, xf, acc[nt], 0, 0, 0);
      }
    }

    // ---- store: lane writes 4 consecutive dims of its own row per tile ----
#pragma unroll
    for (int t = 0; t < 12; ++t) {
      u16* bp = (t < 4) ? Qo : (t < 8) ? Ko : Vo;
      const int d = (t & 3) * 16 + g * 4;
      u16x4 pk;
      pk[0] = f2bf(acc[t][0]); pk[1] = f2bf(acc[t][1]);
      pk[2] = f2bf(acc[t][2]); pk[3] = f2bf(acc[t][3]);
      *reinterpret_cast<u16x4*>(bp + mrow * 64 + d) = pk;
    }
  }
}

// ---------------------------------------------------------------------------
// Kernel 2: causal attention, one batch per block, 8 waves of 64 lanes.
// Wave w handles 16-row q-tiles {w, 15-w} -> balanced 5 kv-chunks each.
// LDS: Ksm[256][64] swz (32KB) | Vt[64][256] swz (32KB) | P[wave][16][64] (16KB)
// ---------------------------------------------------------------------------
__global__ __launch_bounds__(512) void attn_kernel(
    const u16* __restrict__ Qw, const u16* __restrict__ Kw,
    const u16* __restrict__ Vw, float* __restrict__ out)
{
  __shared__ char smem[32768 + 32768 + 16384];
  char* Vt = smem + 32768;
  const int tid = threadIdx.x;
  const int l = tid & 63, w = tid >> 6;
  const int g = l >> 4, li = l & 15;
  const long base = (long)blockIdx.x * (256 * 64);

  // ---- stage K (row-major, swizzled) ----
#pragma unroll
  for (int i = 0; i < 4; ++i) {
    int id = tid + 512 * i;                // 2048 chunks
    int row = id >> 3, slot = id & 7;
    s16x8 v = *reinterpret_cast<const s16x8*>(Kw + base + row * 64 + slot * 8);
    *reinterpret_cast<s16x8*>(smem + row * 128 + ((slot ^ (row & 7)) << 4)) = v;
  }
  // ---- stage V transposed: Vt[d][kv], swizzled ----
#pragma unroll
  for (int i = 0; i < 4; ++i) {
    int id = tid + 512 * i;
    int row = id >> 3, slot = id & 7;
    s16x8 v = *reinterpret_cast<const s16x8*>(Vw + base + row * 64 + slot * 8);
#pragma unroll
    for (int j = 0; j < 8; ++j) {
      int d = slot * 8 + j;
      *reinterpret_cast<u16*>(Vt + d * 512 + ((row * 2) ^ ((d & 7) << 4))) =
          (u16)(unsigned short)v[j];
    }
  }
  __syncthreads();

  char* Pw = smem + 65536 + w * 2048;      // per-wave P buffer [16][64] bf16

  for (int half = 0; half < 2; ++half) {
    const int qt = half ? (15 - w) : w;
    s16x8 qf[2];
#pragma unroll
    for (int dk = 0; dk < 2; ++dk)
      qf[dk] = *reinterpret_cast<const s16x8*>(
          Qw + base + (qt * 16 + li) * 64 + dk * 32 + g * 8);

    f32x4 o[4];
    float m[4], lsum[4];
#pragma unroll
    for (int r = 0; r < 4; ++r) { m[r] = -1e30f; lsum[r] = 0.f; }
#pragma unroll
    for (int nd = 0; nd < 4; ++nd) o[nd] = (f32x4){0.f, 0.f, 0.f, 0.f};

    const int nc = (qt >> 2) + 1;
    for (int c = 0; c < nc; ++c) {
      // ---- S = Q K^T ----
      f32x4 s[4];
#pragma unroll
      for (int nj = 0; nj < 4; ++nj) s[nj] = (f32x4){0.f, 0.f, 0.f, 0.f};
#pragma unroll
      for (int dk = 0; dk < 2; ++dk) {
#pragma unroll
        for (int nj = 0; nj < 4; ++nj) {
          int rb = c * 64 + nj * 16 + li;
          s16x8 kf = *reinterpret_cast<const s16x8*>(
              smem + rb * 128 + (((dk * 4 + g) ^ (rb & 7)) << 4));
          s[nj] = MFMA16(qf[dk], kf, s[nj], 0, 0, 0);
        }
      }
      const bool last = (c == nc - 1);
      // ---- scale + causal mask ----
#pragma unroll
      for (int nj = 0; nj < 4; ++nj)
#pragma unroll
        for (int r = 0; r < 4; ++r) {
          float v = s[nj][r] * 0.125f;
          if (last && (c * 64 + nj * 16 + li) > (qt * 16 + g * 4 + r)) v = -1e30f;
          s[nj][r] = v;
        }
      // ---- online max ----
      float alpha[4];
#pragma unroll
      for (int r = 0; r < 4; ++r) {
        float pm = fmaxf(fmaxf(s[0][r], s[1][r]), fmaxf(s[2][r], s[3][r]));
        pm = fmaxf(pm, __shfl_xor(pm, 1));
        pm = fmaxf(pm, __shfl_xor(pm, 2));
        pm = fmaxf(pm, __shfl_xor(pm, 4));
        pm = fmaxf(pm, __shfl_xor(pm, 8));
        float mn = fmaxf(m[r], pm);
        alpha[r] = __expf(m[r] - mn);
        m[r] = mn;
      }
      // ---- P = exp(S-m), write bf16 to per-wave LDS (swizzled) ----
      float psum[4] = {0.f, 0.f, 0.f, 0.f};
#pragma unroll
      for (int nj = 0; nj < 4; ++nj)
#pragma unroll
        for (int r = 0; r < 4; ++r) {
          float p = __expf(s[nj][r] - m[r]);
          psum[r] += p;
          int row = g * 4 + r;
          *reinterpret_cast<u16*>(
              Pw + row * 128 + ((nj * 32 + li * 2) ^ ((row & 7) << 4))) = f2bf(p);
        }
#pragma unroll
      for (int r = 0; r < 4; ++r) {
        float ps = psum[r];
        ps += __shfl_xor(ps, 1);
        ps += __shfl_xor(ps, 2);
        ps += __shfl_xor(ps, 4);
        ps += __shfl_xor(ps, 8);
        lsum[r] = lsum[r] * alpha[r] + ps;
      }
#pragma unroll
      for (int nd = 0; nd < 4; ++nd)
#pragma unroll
        for (int r = 0; r < 4; ++r) o[nd][r] *= alpha[r];

      __asm__ volatile("s_waitcnt lgkmcnt(0)" ::: "memory");
      // ---- O += P V ----
      s16x8 pa[2];
#pragma unroll
      for (int kk = 0; kk < 2; ++kk)
        pa[kk] = *reinterpret_cast<const s16x8*>(
            Pw + li * 128 + (((kk * 4 + g) ^ (li & 7)) << 4));
#pragma unroll
      for (int nd = 0; nd < 4; ++nd) {
#pragma unroll
        for (int kk = 0; kk < 2; ++kk) {
          int d = nd * 16 + li;
          s16x8 vf = *reinterpret_cast<const s16x8*>(
              Vt + d * 512 + ((c * 128 + kk * 64 + g * 16) ^ ((d & 7) << 4)));
          o[nd] = MFMA16(pa[kk], vf, o[nd], 0, 0, 0);
        }
      }
    }
    // ---- epilogue ----
#pragma unroll
    for (int r = 0; r < 4; ++r) lsum[r] = 1.f / lsum[r];
#pragma unroll
    for (int nd = 0; nd < 4; ++nd)
#pragma unroll
      for (int r = 0; r < 4; ++r)
        out[base + (qt * 16 + g * 4 + r) * 64 + nd * 16 + li] = o[nd][r] * lsum[r];
  }
}

extern "C" void kernel_launch(void* const* d_in, const int* in_sizes, int n_in,
                              void* d_out, int out_size, void* d_ws, size_t ws_size,
                              hipStream_t stream) {
  const float* x  = (const float*)d_in[0];
  const float* WQ = (const float*)d_in[1];
  const float* WK = (const float*)d_in[2];
  const float* WV = (const float*)d_in[3];
  float* out = (float*)d_out;

  // workspace: Q | K | V bf16, each 512*256*64 elems = 16 MiB
  char* ws = (char*)d_ws;
  u16* Qo = (u16*)(ws);
  u16* Ko = (u16*)(ws + 16777216);
  u16* Vo = (u16*)(ws + 2 * 16777216);

  qkv_kernel<<<dim3(256), dim3(512), 0, stream>>>(x, WQ, WK, WV, Qo, Ko, Vo);
  attn_kernel<<<dim3(512), dim3(512), 0, stream>>>(Qo, Ko, Vo, out);
}

// Round 5
// 62.430 us; speedup vs baseline: 5.5848x; 5.5848x over previous
//
#include <hip/hip_runtime.h>

// Head: FULLY FUSED QKV projection + causal attention, MI355X (gfx950)
// B=512, T=256, C=384, D=64. fp32 in/out, bf16 MFMA compute.
// One block = one batch. 1024 threads = 16 waves, 152 KB LDS, 1 block/CU.

typedef short s16x8 __attribute__((ext_vector_type(8)));
typedef float f32x4 __attribute__((ext_vector_type(4)));
typedef unsigned short u16;
typedef unsigned short u16x4 __attribute__((ext_vector_type(4)));

__device__ __forceinline__ u16 f2bf(float f) {
  unsigned u = __builtin_bit_cast(unsigned, f);
  u = (u + 0x7fffu + ((u >> 16) & 1u)) >> 16;   // RNE
  return (u16)u;
}

__device__ __forceinline__ s16x8 pack8(float4 a, float4 b) {
  s16x8 h;
  h[0] = (short)f2bf(a.x); h[1] = (short)f2bf(a.y);
  h[2] = (short)f2bf(a.z); h[3] = (short)f2bf(a.w);
  h[4] = (short)f2bf(b.x); h[5] = (short)f2bf(b.y);
  h[6] = (short)f2bf(b.z); h[7] = (short)f2bf(b.w);
  return h;
}

#define MFMA16 __builtin_amdgcn_mfma_f32_16x16x32_bf16

// LDS layout (bytes):
//  [0,32768)      xc double buffer (2 x 256x32 bf16 = 2x16KB); phase2: P[16][2KB]
//  [32768,57344)  Wc double buffer (2 x 192x32 bf16 = 2x12KB)
//  [57344,90112)  Q  [256][64] bf16, row-swizzled
//  [90112,122880) K  [256][64] bf16, row-swizzled
//  [122880,155648)V^T[64][256] bf16, round-1 layout
#define XC(b) ((b) * 16384)
#define WC(b) (32768 + (b) * 12288)
#define QS 57344
#define KS 90112
#define VS 122880

__global__ __launch_bounds__(1024) void head_kernel(
    const float* __restrict__ x,
    const float* __restrict__ WQ, const float* __restrict__ WK,
    const float* __restrict__ WV, float* __restrict__ out)
{
  __shared__ char smem[155648];
  const int tid = threadIdx.x;
  const int l  = tid & 63;
  const int w  = tid >> 6;
  const int g  = l >> 4, li = l & 15;
  const long xbase = (long)blockIdx.x * (256 * 384);
  const long obase = (long)blockIdx.x * (256 * 64);

  // staging coords: 1024 chunks of 8 floats for xc; 768 for Wc
  const int srow  = tid >> 2;          // 0..255
  const int sslot = tid & 3;           // 0..3 (16B slots of a 64B LDS row)
  const bool do_w = (tid < 768);       // waves 0..11 stage W rows 0..191
  const float* wrp = nullptr;
  if (do_w)
    wrp = (srow < 64) ? (WQ + srow * 384)
         : (srow < 128) ? (WK + (srow - 64) * 384)
                        : (WV + (srow - 128) * 384);
  const int wswz = (srow >> 1) & 3;    // write-side swizzle
  const int rswz = (li >> 1) & 3;      // read-side swizzle

  // ---- prologue: stage k-tile 0 into buffer 0 ----
  {
    const float* px = x + xbase + srow * 384 + sslot * 8;
    float4 xa = *reinterpret_cast<const float4*>(px);
    float4 xb = *reinterpret_cast<const float4*>(px + 4);
    *reinterpret_cast<s16x8*>(smem + XC(0) + srow * 64 + ((sslot ^ wswz) << 4)) =
        pack8(xa, xb);
    if (do_w) {
      float4 wa = *reinterpret_cast<const float4*>(wrp + sslot * 8);
      float4 wb = *reinterpret_cast<const float4*>(wrp + sslot * 8 + 4);
      *reinterpret_cast<s16x8*>(smem + WC(0) + srow * 64 + ((sslot ^ wswz) << 4)) =
          pack8(wa, wb);
    }
  }
  __syncthreads();

  f32x4 acc[12];
#pragma unroll
  for (int nt = 0; nt < 12; ++nt) acc[nt] = (f32x4){0.f, 0.f, 0.f, 0.f};

  // ---- phase 1: 12 k-tiles, 2-phase overlap, one barrier per tile ----
#pragma unroll 1
  for (int t = 0; t < 12; ++t) {
    float4 xa, xb, wa, wb;
    if (t < 11) {                       // issue next tile's loads (regs)
      const float* px = x + xbase + srow * 384 + (t + 1) * 32 + sslot * 8;
      xa = *reinterpret_cast<const float4*>(px);
      xb = *reinterpret_cast<const float4*>(px + 4);
      if (do_w) {
        wa = *reinterpret_cast<const float4*>(wrp + (t + 1) * 32 + sslot * 8);
        wb = *reinterpret_cast<const float4*>(wrp + (t + 1) * 32 + sslot * 8 + 4);
      }
    }
    const int cb = t & 1;
    // B-frag: this wave's 16 x-rows, k-slot g
    s16x8 bf = *reinterpret_cast<const s16x8*>(
        smem + XC(cb) + (16 * w + li) * 64 + ((g ^ rswz) << 4));
    // A-frags (W rows) in 3 groups of 4, MFMA into acc
#pragma unroll
    for (int h = 0; h < 3; ++h) {
      s16x8 af[4];
#pragma unroll
      for (int j = 0; j < 4; ++j)
        af[j] = *reinterpret_cast<const s16x8*>(
            smem + WC(cb) + ((h * 4 + j) * 16 + li) * 64 + ((g ^ rswz) << 4));
#pragma unroll
      for (int j = 0; j < 4; ++j)
        acc[h * 4 + j] = MFMA16(af[j], bf, acc[h * 4 + j], 0, 0, 0);
    }
    if (t < 11) {                       // convert + write next tile's buffers
      *reinterpret_cast<s16x8*>(
          smem + XC(cb ^ 1) + srow * 64 + ((sslot ^ wswz) << 4)) = pack8(xa, xb);
      if (do_w)
        *reinterpret_cast<s16x8*>(
            smem + WC(cb ^ 1) + srow * 64 + ((sslot ^ wswz) << 4)) = pack8(wa, wb);
    }
    __syncthreads();
  }

  // ---- phase-1 epilogue: acc -> Q,K (row-major swz) and V (transposed) ----
  // C/D: lane holds out[n = nt*16 + g*4 + r][x-row = 16w + li]
  {
    const int row = 16 * w + li;
#pragma unroll
    for (int nt = 0; nt < 8; ++nt) {
      const int b0 = (nt < 4) ? QS : KS;
      const int slot = (nt & 3) * 2 + (g >> 1);   // ((nt&3)*32+g*8)>>4
      u16x4 pk;
      pk[0] = f2bf(acc[nt][0]); pk[1] = f2bf(acc[nt][1]);
      pk[2] = f2bf(acc[nt][2]); pk[3] = f2bf(acc[nt][3]);
      *reinterpret_cast<u16x4*>(
          smem + b0 + row * 128 + ((slot ^ (row & 7)) << 4) + (g & 1) * 8) = pk;
    }
#pragma unroll
    for (int nt = 8; nt < 12; ++nt)
#pragma unroll
      for (int r = 0; r < 4; ++r) {
        int d = (nt - 8) * 16 + g * 4 + r;
        *reinterpret_cast<u16*>(
            smem + VS + d * 512 + ((row * 2) ^ ((d & 7) << 4))) = f2bf(acc[nt][r]);
      }
  }
  __syncthreads();

  // ---- phase 2: causal attention; wave w owns q-tile qt = w ----
  char* Pw = smem + w * 2048;           // overlays retired xc buffers
  const int qt = w;
  s16x8 qf[2];
#pragma unroll
  for (int dk = 0; dk < 2; ++dk) {
    int row = qt * 16 + li;
    qf[dk] = *reinterpret_cast<const s16x8*>(
        smem + QS + row * 128 + (((dk * 4 + g) ^ (row & 7)) << 4));
  }

  f32x4 o[4];
  float m[4], lsum[4];
#pragma unroll
  for (int r = 0; r < 4; ++r) { m[r] = -1e30f; lsum[r] = 0.f; }
#pragma unroll
  for (int nd = 0; nd < 4; ++nd) o[nd] = (f32x4){0.f, 0.f, 0.f, 0.f};

  const int nc = (qt >> 2) + 1;
#pragma unroll 1
  for (int c = 0; c < nc; ++c) {
    // ---- S = Q K^T ----
    f32x4 s[4];
#pragma unroll
    for (int nj = 0; nj < 4; ++nj) s[nj] = (f32x4){0.f, 0.f, 0.f, 0.f};
#pragma unroll
    for (int dk = 0; dk < 2; ++dk) {
#pragma unroll
      for (int nj = 0; nj < 4; ++nj) {
        int rb = c * 64 + nj * 16 + li;
        s16x8 kf = *reinterpret_cast<const s16x8*>(
            smem + KS + rb * 128 + (((dk * 4 + g) ^ (rb & 7)) << 4));
        s[nj] = MFMA16(qf[dk], kf, s[nj], 0, 0, 0);
      }
    }
    const bool last = (c == nc - 1);
    // ---- scale + causal mask ----
#pragma unroll
    for (int nj = 0; nj < 4; ++nj)
#pragma unroll
      for (int r = 0; r < 4; ++r) {
        float v = s[nj][r] * 0.125f;
        if (last && (c * 64 + nj * 16 + li) > (qt * 16 + g * 4 + r)) v = -1e30f;
        s[nj][r] = v;
      }
    // ---- online max ----
    float alpha[4];
#pragma unroll
    for (int r = 0; r < 4; ++r) {
      float pm = fmaxf(fmaxf(s[0][r], s[1][r]), fmaxf(s[2][r], s[3][r]));
      pm = fmaxf(pm, __shfl_xor(pm, 1));
      pm = fmaxf(pm, __shfl_xor(pm, 2));
      pm = fmaxf(pm, __shfl_xor(pm, 4));
      pm = fmaxf(pm, __shfl_xor(pm, 8));
      float mn = fmaxf(m[r], pm);
      alpha[r] = __expf(m[r] - mn);
      m[r] = mn;
    }
    // ---- P = exp(S-m) -> per-wave LDS (swizzled) ----
    float psum[4] = {0.f, 0.f, 0.f, 0.f};
#pragma unroll
    for (int nj = 0; nj < 4; ++nj)
#pragma unroll
      for (int r = 0; r < 4; ++r) {
        float p = __expf(s[nj][r] - m[r]);
        psum[r] += p;
        int rowp = g * 4 + r;
        *reinterpret_cast<u16*>(
            Pw + rowp * 128 + ((nj * 32 + li * 2) ^ ((rowp & 7) << 4))) = f2bf(p);
      }
#pragma unroll
    for (int r = 0; r < 4; ++r) {
      float ps = psum[r];
      ps += __shfl_xor(ps, 1);
      ps += __shfl_xor(ps, 2);
      ps += __shfl_xor(ps, 4);
      ps += __shfl_xor(ps, 8);
      lsum[r] = lsum[r] * alpha[r] + ps;
    }
#pragma unroll
    for (int nd = 0; nd < 4; ++nd)
#pragma unroll
      for (int r = 0; r < 4; ++r) o[nd][r] *= alpha[r];

    __asm__ volatile("s_waitcnt lgkmcnt(0)" ::: "memory");
    // ---- O += P V ----
    s16x8 pa[2];
#pragma unroll
    for (int kk = 0; kk < 2; ++kk)
      pa[kk] = *reinterpret_cast<const s16x8*>(
          Pw + li * 128 + (((kk * 4 + g) ^ (li & 7)) << 4));
#pragma unroll
    for (int nd = 0; nd < 4; ++nd) {
#pragma unroll
      for (int kk = 0; kk < 2; ++kk) {
        int d = nd * 16 + li;
        s16x8 vf = *reinterpret_cast<const s16x8*>(
            smem + VS + d * 512 + ((c * 128 + kk * 64 + g * 16) ^ ((d & 7) << 4)));
        o[nd] = MFMA16(pa[kk], vf, o[nd], 0, 0, 0);
      }
    }
  }
  // ---- output ----
#pragma unroll
  for (int r = 0; r < 4; ++r) lsum[r] = 1.f / lsum[r];
#pragma unroll
  for (int nd = 0; nd < 4; ++nd)
#pragma unroll
    for (int r = 0; r < 4; ++r)
      out[obase + (qt * 16 + g * 4 + r) * 64 + nd * 16 + li] = o[nd][r] * lsum[r];
}

extern "C" void kernel_launch(void* const* d_in, const int* in_sizes, int n_in,
                              void* d_out, int out_size, void* d_ws, size_t ws_size,
                              hipStream_t stream) {
  const float* x  = (const float*)d_in[0];
  const float* WQ = (const float*)d_in[1];
  const float* WK = (const float*)d_in[2];
  const float* WV = (const float*)d_in[3];
  float* out = (float*)d_out;

  head_kernel<<<dim3(512), dim3(1024), 0, stream>>>(x, WQ, WK, WV, out);
}

// Round 6
// 62.009 us; speedup vs baseline: 5.6228x; 1.0068x over previous
//
#include <hip/hip_runtime.h>

// Head: FULLY FUSED QKV projection + causal attention, MI355X (gfx950)
// B=512, T=256, C=384, D=64. fp32 in/out, bf16 MFMA compute.
// One block = one batch. 1024 threads = 16 waves, 152 KB LDS, 1 block/CU.

typedef short s16x8 __attribute__((ext_vector_type(8)));
typedef float f32x4 __attribute__((ext_vector_type(4)));
typedef float f32x2 __attribute__((ext_vector_type(2)));
typedef unsigned int u32;
typedef unsigned int u32x4 __attribute__((ext_vector_type(4)));
typedef unsigned short u16;
typedef unsigned short u16x4 __attribute__((ext_vector_type(4)));
typedef __bf16 bf16x2 __attribute__((ext_vector_type(2)));

// HW bf16 convert (RNE): lowers to v_cvt_pk_bf16_f32 on gfx950.
__device__ __forceinline__ u32 cvt2(float x, float y) {
  f32x2 v = {x, y};
  bf16x2 b = __builtin_convertvector(v, bf16x2);
  return __builtin_bit_cast(u32, b);
}
__device__ __forceinline__ u16 f2bf(float f) {
  __bf16 b = (__bf16)f;
  return __builtin_bit_cast(u16, b);
}
__device__ __forceinline__ s16x8 pack8(float4 a, float4 b) {
  u32x4 p = {cvt2(a.x, a.y), cvt2(a.z, a.w), cvt2(b.x, b.y), cvt2(b.z, b.w)};
  return __builtin_bit_cast(s16x8, p);
}

#define MFMA16 __builtin_amdgcn_mfma_f32_16x16x32_bf16

// LDS layout (bytes):
//  [0,32768)      xc double buffer (2 x 256x32 bf16 = 2x16KB); phase2: P[16][2KB]
//  [32768,57344)  Wc double buffer (2 x 192x32 bf16 = 2x12KB)
//  [57344,90112)  Q  [256][64] bf16, row-swizzled
//  [90112,122880) K  [256][64] bf16, row-swizzled
//  [122880,155648)V^T[64][256] bf16, round-1 layout
#define XC(b) ((b) * 16384)
#define WC(b) (32768 + (b) * 12288)
#define QS 57344
#define KS 90112
#define VS 122880

__global__ __launch_bounds__(1024) void head_kernel(
    const float* __restrict__ x,
    const float* __restrict__ WQ, const float* __restrict__ WK,
    const float* __restrict__ WV, float* __restrict__ out)
{
  __shared__ char smem[155648];
  const int tid = threadIdx.x;
  const int l  = tid & 63;
  const int w  = tid >> 6;
  const int g  = l >> 4, li = l & 15;
  const int wr = w >> 2, wc = w & 3;     // 4x4 wave grid for phase 1
  const long xbase = (long)blockIdx.x * (256 * 384);
  const long obase = (long)blockIdx.x * (256 * 64);

  // staging coords: 1024 chunks of 8 floats for xc; 768 for Wc
  const int srow  = tid >> 2;          // 0..255
  const int sslot = tid & 3;           // 0..3 (16B slots of a 64B LDS row)
  const bool do_w = (tid < 768);       // waves 0..11 stage W rows 0..191
  const float* wrp = nullptr;
  if (do_w)
    wrp = (srow < 64) ? (WQ + srow * 384)
         : (srow < 128) ? (WK + (srow - 64) * 384)
                        : (WV + (srow - 128) * 384);
  const int wswz = (srow >> 1) & 3;    // write-side swizzle
  const int rswz = (li >> 1) & 3;      // read-side swizzle

  // ---- prologue: stage k-tile 0 into buffer 0 ----
  {
    const float* px = x + xbase + srow * 384 + sslot * 8;
    float4 xa = *reinterpret_cast<const float4*>(px);
    float4 xb = *reinterpret_cast<const float4*>(px + 4);
    *reinterpret_cast<s16x8*>(smem + XC(0) + srow * 64 + ((sslot ^ wswz) << 4)) =
        pack8(xa, xb);
    if (do_w) {
      float4 wa = *reinterpret_cast<const float4*>(wrp + sslot * 8);
      float4 wb = *reinterpret_cast<const float4*>(wrp + sslot * 8 + 4);
      *reinterpret_cast<s16x8*>(smem + WC(0) + srow * 64 + ((sslot ^ wswz) << 4)) =
          pack8(wa, wb);
    }
  }
  __syncthreads();

  f32x4 acc[4][3];   // [bi = 16-row tile][ai = 16-col tile]
#pragma unroll
  for (int bi = 0; bi < 4; ++bi)
#pragma unroll
    for (int ai = 0; ai < 3; ++ai)
      acc[bi][ai] = (f32x4){0.f, 0.f, 0.f, 0.f};

  // ---- phase 1: 12 k-tiles, 2-phase overlap, one barrier per tile ----
#pragma unroll 1
  for (int t = 0; t < 12; ++t) {
    float4 xa, xb, wa, wb;
    if (t < 11) {                       // issue next tile's loads (regs)
      const float* px = x + xbase + srow * 384 + (t + 1) * 32 + sslot * 8;
      xa = *reinterpret_cast<const float4*>(px);
      xb = *reinterpret_cast<const float4*>(px + 4);
      if (do_w) {
        wa = *reinterpret_cast<const float4*>(wrp + (t + 1) * 32 + sslot * 8);
        wb = *reinterpret_cast<const float4*>(wrp + (t + 1) * 32 + sslot * 8 + 4);
      }
    }
    const int cb = t & 1;
    // 4 B-frags (this wave's 64 x-rows) + 3 A-frags (48 W-cols), 12 MFMA
    s16x8 bf[4];
#pragma unroll
    for (int bi = 0; bi < 4; ++bi)
      bf[bi] = *reinterpret_cast<const s16x8*>(
          smem + XC(cb) + (wr * 64 + bi * 16 + li) * 64 + ((g ^ rswz) << 4));
    s16x8 af[3];
#pragma unroll
    for (int ai = 0; ai < 3; ++ai)
      af[ai] = *reinterpret_cast<const s16x8*>(
          smem + WC(cb) + (wc * 48 + ai * 16 + li) * 64 + ((g ^ rswz) << 4));
#pragma unroll
    for (int bi = 0; bi < 4; ++bi)
#pragma unroll
      for (int ai = 0; ai < 3; ++ai)
        acc[bi][ai] = MFMA16(af[ai], bf[bi], acc[bi][ai], 0, 0, 0);

    if (t < 11) {                       // convert + write next tile's buffers
      *reinterpret_cast<s16x8*>(
          smem + XC(cb ^ 1) + srow * 64 + ((sslot ^ wswz) << 4)) = pack8(xa, xb);
      if (do_w)
        *reinterpret_cast<s16x8*>(
            smem + WC(cb ^ 1) + srow * 64 + ((sslot ^ wswz) << 4)) = pack8(wa, wb);
    }
    __syncthreads();
  }

  // ---- phase-1 epilogue: acc -> Q,K (row-major swz) and V (transposed) ----
  // C/D: lane holds D[n = wc*48 + ai*16 + g*4 + r][row = wr*64 + bi*16 + li]
#pragma unroll
  for (int bi = 0; bi < 4; ++bi) {
    const int row = wr * 64 + bi * 16 + li;
#pragma unroll
    for (int ai = 0; ai < 3; ++ai) {
      const int nb = wc * 48 + ai * 16;
      if (nb < 128) {                   // Q or K: row-major swizzled u16x4
        const int b0 = (nb < 64) ? QS : KS;
        const int d16 = nb & 63;
        const int slot = (d16 >> 3) + (g >> 1);
        u16x4 pk;
        pk[0] = f2bf(acc[bi][ai][0]); pk[1] = f2bf(acc[bi][ai][1]);
        pk[2] = f2bf(acc[bi][ai][2]); pk[3] = f2bf(acc[bi][ai][3]);
        *reinterpret_cast<u16x4*>(
            smem + b0 + row * 128 + ((slot ^ (row & 7)) << 4) + (g & 1) * 8) = pk;
      } else {                          // V: transposed layout
#pragma unroll
        for (int r = 0; r < 4; ++r) {
          int d = nb - 128 + g * 4 + r;
          *reinterpret_cast<u16*>(
              smem + VS + d * 512 + ((row * 2) ^ ((d & 7) << 4))) =
              f2bf(acc[bi][ai][r]);
        }
      }
    }
  }
  __syncthreads();

  // ---- phase 2: causal attention; wave w owns q-tile qt = w ----
  char* Pw = smem + w * 2048;           // overlays retired xc buffers
  const int qt = w;
  s16x8 qf[2];
#pragma unroll
  for (int dk = 0; dk < 2; ++dk) {
    int row = qt * 16 + li;
    qf[dk] = *reinterpret_cast<const s16x8*>(
        smem + QS + row * 128 + (((dk * 4 + g) ^ (row & 7)) << 4));
  }

  f32x4 o[4];
  float m[4], lsum[4];
#pragma unroll
  for (int r = 0; r < 4; ++r) { m[r] = -1e30f; lsum[r] = 0.f; }
#pragma unroll
  for (int nd = 0; nd < 4; ++nd) o[nd] = (f32x4){0.f, 0.f, 0.f, 0.f};

  const int nc = (qt >> 2) + 1;
#pragma unroll 1
  for (int c = 0; c < nc; ++c) {
    // ---- S = Q K^T ----
    f32x4 s[4];
#pragma unroll
    for (int nj = 0; nj < 4; ++nj) s[nj] = (f32x4){0.f, 0.f, 0.f, 0.f};
#pragma unroll
    for (int dk = 0; dk < 2; ++dk) {
#pragma unroll
      for (int nj = 0; nj < 4; ++nj) {
        int rb = c * 64 + nj * 16 + li;
        s16x8 kf = *reinterpret_cast<const s16x8*>(
            smem + KS + rb * 128 + (((dk * 4 + g) ^ (rb & 7)) << 4));
        s[nj] = MFMA16(qf[dk], kf, s[nj], 0, 0, 0);
      }
    }
    const bool last = (c == nc - 1);
    // ---- scale + causal mask ----
#pragma unroll
    for (int nj = 0; nj < 4; ++nj)
#pragma unroll
      for (int r = 0; r < 4; ++r) {
        float v = s[nj][r] * 0.125f;
        if (last && (c * 64 + nj * 16 + li) > (qt * 16 + g * 4 + r)) v = -1e30f;
        s[nj][r] = v;
      }
    // ---- online max ----
    float alpha[4];
#pragma unroll
    for (int r = 0; r < 4; ++r) {
      float pm = fmaxf(fmaxf(s[0][r], s[1][r]), fmaxf(s[2][r], s[3][r]));
      pm = fmaxf(pm, __shfl_xor(pm, 1));
      pm = fmaxf(pm, __shfl_xor(pm, 2));
      pm = fmaxf(pm, __shfl_xor(pm, 4));
      pm = fmaxf(pm, __shfl_xor(pm, 8));
      float mn = fmaxf(m[r], pm);
      alpha[r] = __expf(m[r] - mn);
      m[r] = mn;
    }
    // ---- P = exp(S-m) -> per-wave LDS (swizzled) ----
    float psum[4] = {0.f, 0.f, 0.f, 0.f};
#pragma unroll
    for (int nj = 0; nj < 4; ++nj)
#pragma unroll
      for (int r = 0; r < 4; ++r) {
        float p = __expf(s[nj][r] - m[r]);
        psum[r] += p;
        int rowp = g * 4 + r;
        *reinterpret_cast<u16*>(
            Pw + rowp * 128 + ((nj * 32 + li * 2) ^ ((rowp & 7) << 4))) = f2bf(p);
      }
#pragma unroll
    for (int r = 0; r < 4; ++r) {
      float ps = psum[r];
      ps += __shfl_xor(ps, 1);
      ps += __shfl_xor(ps, 2);
      ps += __shfl_xor(ps, 4);
      ps += __shfl_xor(ps, 8);
      lsum[r] = lsum[r] * alpha[r] + ps;
    }
#pragma unroll
    for (int nd = 0; nd < 4; ++nd)
#pragma unroll
      for (int r = 0; r < 4; ++r) o[nd][r] *= alpha[r];

    __asm__ volatile("s_waitcnt lgkmcnt(0)" ::: "memory");
    // ---- O += P V ----
    s16x8 pa[2];
#pragma unroll
    for (int kk = 0; kk < 2; ++kk)
      pa[kk] = *reinterpret_cast<const s16x8*>(
          Pw + li * 128 + (((kk * 4 + g) ^ (li & 7)) << 4));
#pragma unroll
    for (int nd = 0; nd < 4; ++nd) {
#pragma unroll
      for (int kk = 0; kk < 2; ++kk) {
        int d = nd * 16 + li;
        s16x8 vf = *reinterpret_cast<const s16x8*>(
            smem + VS + d * 512 + ((c * 128 + kk * 64 + g * 16) ^ ((d & 7) << 4)));
        o[nd] = MFMA16(pa[kk], vf, o[nd], 0, 0, 0);
      }
    }
  }
  // ---- output ----
#pragma unroll
  for (int r = 0; r < 4; ++r) lsum[r] = 1.f / lsum[r];
#pragma unroll
  for (int nd = 0; nd < 4; ++nd)
#pragma unroll
    for (int r = 0; r < 4; ++r)
      out[obase + (qt * 16 + g * 4 + r) * 64 + nd * 16 + li] = o[nd][r] * lsum[r];
}

extern "C" void kernel_launch(void* const* d_in, const int* in_sizes, int n_in,
                              void* d_out, int out_size, void* d_ws, size_t ws_size,
                              hipStream_t stream) {
  const float* x  = (const float*)d_in[0];
  const float* WQ = (const float*)d_in[1];
  const float* WK = (const float*)d_in[2];
  const float* WV = (const float*)d_in[3];
  float* out = (float*)d_out;

  head_kernel<<<dim3(512), dim3(1024), 0, stream>>>(x, WQ, WK, WV, out);
}